// Round 1
// 250.148 us; speedup vs baseline: 1.0016x; 1.0016x over previous
//
#include <hip/hip_runtime.h>

#define ITERS 20
#define EPS 1e-9f

typedef float v2f __attribute__((ext_vector_type(2)));

// One wave (64 lanes) per 64x64 matrix. Lane (bi,bj) owns the 8x8 sub-block
// rows [8bi,8bi+8), cols [8bj,8bj+8). Sinkhorn iterate M = E .* (u v^T): only
// u,v update; E = exp(x) stays in registers (as float2 pairs for v_pk_fma_f32).
//
// Cross-lane reduces: strides 1,2,4(->xor7),8 via DPP (VALU); strides 16,32 via
// gfx950 v_permlane{16,32}_swap_b32 (also VALU) -- NO DS-pipe ops in the loop.

template <int CTRL>
__device__ __forceinline__ float dpp_add(float x) {
    int yi = __builtin_amdgcn_update_dpp(0, __float_as_int(x), CTRL, 0xf, 0xf, true);
    return x + __int_as_float(yi);
}

#if __has_builtin(__builtin_amdgcn_permlane16_swap)
// r0/r1 with identical inputs: r0 holds even 16-rows replicated, r1 odd rows;
// r0 + r1 == xor16 butterfly all-reduce, pure VALU.
__device__ __forceinline__ float xadd16(float x) {
    unsigned u = __float_as_uint(x);
    auto r = __builtin_amdgcn_permlane16_swap(u, u, false, false);
    return __uint_as_float(r[0]) + __uint_as_float(r[1]);
}
#else
__device__ __forceinline__ float xadd16(float x) {
    // ds_swizzle xor16: offset = (16<<10) | 0x1F
    return x + __int_as_float(__builtin_amdgcn_ds_swizzle(__float_as_int(x), 0x401F));
}
#endif

#if __has_builtin(__builtin_amdgcn_permlane32_swap)
__device__ __forceinline__ float xadd32(float x) {
    unsigned u = __float_as_uint(x);
    auto r = __builtin_amdgcn_permlane32_swap(u, u, false, false);
    return __uint_as_float(r[0]) + __uint_as_float(r[1]);
}
#else
__device__ __forceinline__ float xadd32(float x) {
    return x + __shfl_xor(x, 32, 64);
}
#endif

__global__ __launch_bounds__(256, 4) void sinkhorn_kernel(
        const float* __restrict__ x, float* __restrict__ out, int nmat) {
    const int lane = threadIdx.x & 63;
    const int wave = threadIdx.x >> 6;
    const int mat  = blockIdx.x * 4 + wave;
    if (mat >= nmat) return;
    const int bi = lane >> 3;   // block-row 0..7
    const int bj = lane & 7;    // block-col 0..7

    const float4* __restrict__ xin = (const float4*)(x + (size_t)mat * 4096);

    // Load 8x8 block as 2 float4 per row, apply exp, keep as float2 pairs.
    v2f b2[8][4];
    #pragma unroll
    for (int r = 0; r < 8; ++r) {
        float4 lo = xin[(8 * bi + r) * 16 + 2 * bj + 0];
        float4 hi = xin[(8 * bi + r) * 16 + 2 * bj + 1];
        b2[r][0] = (v2f){__expf(lo.x), __expf(lo.y)};
        b2[r][1] = (v2f){__expf(lo.z), __expf(lo.w)};
        b2[r][2] = (v2f){__expf(hi.x), __expf(hi.y)};
        b2[r][3] = (v2f){__expf(hi.z), __expf(hi.w)};
    }

    float uu[8];
    v2f   vv2[4];
    #pragma unroll
    for (int i = 0; i < 8; ++i) uu[i] = 1.0f;
    #pragma unroll
    for (int i = 0; i < 4; ++i) vv2[i] = (v2f){1.0f, 1.0f};

    for (int it = 0; it < ITERS; ++it) {
        // ---- row phase: p_i = sum_j E[i,j] v_j  (packed fp32 matvec) ----
        float p[8];
        #pragma unroll
        for (int r = 0; r < 8; ++r) {
            v2f s2 = b2[r][0] * vv2[0];
            s2 += b2[r][1] * vv2[1];
            s2 += b2[r][2] * vv2[2];
            s2 += b2[r][3] * vv2[3];
            p[r] = s2.x + s2.y;
        }
        // all-reduce across the 8 lanes sharing bi (lane bits 0-2) — pure DPP
        #pragma unroll
        for (int r = 0; r < 8; ++r) p[r] = dpp_add<0xB1>(p[r]);   // quad_perm xor1
        #pragma unroll
        for (int r = 0; r < 8; ++r) p[r] = dpp_add<0x4E>(p[r]);   // quad_perm xor2
        #pragma unroll
        for (int r = 0; r < 8; ++r) p[r] = dpp_add<0x141>(p[r]);  // row_half_mirror = xor7
        #pragma unroll
        for (int r = 0; r < 8; ++r) {
            float S = fmaf(uu[r], p[r], EPS);      // rowsum + eps
            uu[r] *= __builtin_amdgcn_rcpf(S);
        }

        // ---- col phase: q_j = sum_i E[i,j] u_i  (packed fp32 matvec) ----
        v2f q2[4];
        #pragma unroll
        for (int c = 0; c < 4; ++c) q2[c] = b2[0][c] * uu[0];
        #pragma unroll
        for (int r = 1; r < 8; ++r) {
            #pragma unroll
            for (int c = 0; c < 4; ++c) q2[c] += b2[r][c] * uu[r];
        }
        // all-reduce across the 8 lanes sharing bj (lane bits 3-5) — all VALU
        #pragma unroll
        for (int c = 0; c < 4; ++c) {
            q2[c].x = dpp_add<0x128>(q2[c].x);     // row_ror:8 = xor8
            q2[c].y = dpp_add<0x128>(q2[c].y);
        }
        #pragma unroll
        for (int c = 0; c < 4; ++c) {
            q2[c].x = xadd16(q2[c].x);             // permlane16_swap
            q2[c].y = xadd16(q2[c].y);
        }
        #pragma unroll
        for (int c = 0; c < 4; ++c) {
            q2[c].x = xadd32(q2[c].x);             // permlane32_swap
            q2[c].y = xadd32(q2[c].y);
        }
        #pragma unroll
        for (int c = 0; c < 4; ++c) {
            float Tx = fmaf(vv2[c].x, q2[c].x, EPS);
            float Ty = fmaf(vv2[c].y, q2[c].y, EPS);
            vv2[c].x *= __builtin_amdgcn_rcpf(Tx);
            vv2[c].y *= __builtin_amdgcn_rcpf(Ty);
        }
    }

    // ---- epilogue: out = E .* (u v^T), packed muls ----
    float4* __restrict__ o = (float4*)(out + (size_t)mat * 4096);
    #pragma unroll
    for (int r = 0; r < 8; ++r) {
        v2f uv0 = vv2[0] * uu[r];
        v2f uv1 = vv2[1] * uu[r];
        v2f uv2 = vv2[2] * uu[r];
        v2f uv3 = vv2[3] * uu[r];
        v2f w0 = b2[r][0] * uv0;
        v2f w1 = b2[r][1] * uv1;
        v2f w2 = b2[r][2] * uv2;
        v2f w3 = b2[r][3] * uv3;
        float4 lo, hi;
        lo.x = w0.x; lo.y = w0.y; lo.z = w1.x; lo.w = w1.y;
        hi.x = w2.x; hi.y = w2.y; hi.z = w3.x; hi.w = w3.y;
        o[(8 * bi + r) * 16 + 2 * bj + 0] = lo;
        o[(8 * bi + r) * 16 + 2 * bj + 1] = hi;
    }
}

extern "C" void kernel_launch(void* const* d_in, const int* in_sizes, int n_in,
                              void* d_out, int out_size, void* d_ws, size_t ws_size,
                              hipStream_t stream) {
    const float* x = (const float*)d_in[0];
    float* out = (float*)d_out;
    const int nmat = in_sizes[0] / 4096;          // 8192 matrices of 64x64
    const int blocks = (nmat + 3) / 4;            // 4 matrices (waves) per block
    sinkhorn_kernel<<<blocks, 256, 0, stream>>>(x, out, nmat);
}